// Round 1
// baseline (439.481 us; speedup 1.0000x reference)
//
#include <hip/hip_runtime.h>
#include <math.h>

// Problem constants
#define KS    11
#define H     512
#define W     512
#define OH    502
#define OW    502
#define NPLANES 48
#define TOTAL_OUT (NPLANES * OH * OW)   // 12,096,192

// Full-width tiles: 512 input cols = 512 threads, 1 col/thread.
// TH=4 output rows per iteration, block marches down a 32-row chunk.
#define TH      4
#define IROWS   (TH + KS - 1)     // 14 input rows per iteration
#define LVW     524               // row stride: 16B-aligned (524%4==0); 524%32==12 spreads bank quads
#define NTHREADS 512
#define CHUNK   32                // output rows per block
#define ITERS   (CHUNK / TH)      // 8
#define NCHUNKS 16                // 16*32 = 512 >= 502

__global__ void zero_out_kernel(float* out) { out[0] = 0.0f; }

__global__ __launch_bounds__(NTHREADS, 6) void ssim_kernel(
    const float* __restrict__ x,
    const float* __restrict__ y,
    const float* __restrict__ win,
    float* __restrict__ out)
{
    // 5 vertically-convolved signals: mu_x, mu_y, xx, yy, xy
    __shared__ __align__(16) float v[5][TH][LVW];   // 41,920 B -> 3 blocks/CU (24 waves = 75%)
    __shared__ float w1s[KS];
    __shared__ float wsum[NTHREADS / 64];

    const int t     = threadIdx.x;          // == input column
    const int chunk = blockIdx.x;           // 0..15
    const int plane = blockIdx.y;           // 0..47

    const float* __restrict__ xp = x + (size_t)plane * (H * W);
    const float* __restrict__ yp = y + (size_t)plane * (H * W);

    // Separable taps: window = outer(g,g) => g[i] = sqrt(win[i][i])
    if (t < KS) w1s[t] = sqrtf(win[t * KS + t]);
    __syncthreads();

    float w[KS];
#pragma unroll
    for (int k = 0; k < KS; k++) w[k] = w1s[k];

    // Stage-2 mapping: 4 rows x 128 col-runs of 4 px. c0 max = 508; reads c0..c0+15 <= 523 < LVW.
    const int r  = t & 3;
    const int c0 = (t >> 2) << 2;
    const float c1 = 1e-4f;   // (0.01)^2
    const float c2 = 9e-4f;   // (0.03)^2
    float acc = 0.f;

    for (int it = 0; it < ITERS; ++it) {
        const int gy0 = chunk * CHUNK + it * TH;
        if (gy0 >= OH) break;               // uniform across block

        // ---- Stage 1: vertical 11-tap conv, 1 column/thread, regs only ----
        float a0[TH], a1[TH], a2[TH], a3[TH], a4[TH];
#pragma unroll
        for (int q = 0; q < TH; q++) { a0[q]=0.f; a1[q]=0.f; a2[q]=0.f; a3[q]=0.f; a4[q]=0.f; }

#pragma unroll
        for (int j = 0; j < IROWS; j++) {
            const int gy = gy0 + j;
            float xv = 0.f, yv = 0.f;
            if (gy < H) {                   // uniform branch
                xv = xp[gy * W + t];
                yv = yp[gy * W + t];
            }
            const float xx = xv * xv;
            const float yy = yv * yv;
            const float xy = xv * yv;
#pragma unroll
            for (int q = 0; q < TH; q++) {
                if (j - q >= 0 && j - q < KS) {   // constant-folds after unroll
                    const float wk = w[j - q];
                    a0[q] += wk * xv;
                    a1[q] += wk * yv;
                    a2[q] += wk * xx;
                    a3[q] += wk * yy;
                    a4[q] += wk * xy;
                }
            }
        }

        __syncthreads();    // WAR: previous iteration's stage-2 reads of v are done
#pragma unroll
        for (int q = 0; q < TH; q++) {      // coalesced b32 stores, lane==col -> conflict-free
            v[0][q][t] = a0[q];
            v[1][q][t] = a1[q];
            v[2][q][t] = a2[q];
            v[3][q][t] = a3[q];
            v[4][q][t] = a4[q];
        }
        __syncthreads();    // v ready

        // ---- Stage 2: horizontal 11-tap conv over 4-px run + SSIM ----
        float mu[5][TH];
#pragma unroll
        for (int s = 0; s < 5; s++) {
            const float* __restrict__ vrow = &v[s][r][c0];   // 16B-aligned (stride 524 words)
            float vs[16];
#pragma unroll
            for (int qq = 0; qq < 4; qq++) {                 // 4x ds_read_b128
                const float4 f4 = *reinterpret_cast<const float4*>(vrow + 4 * qq);
                vs[4*qq+0] = f4.x; vs[4*qq+1] = f4.y; vs[4*qq+2] = f4.z; vs[4*qq+3] = f4.w;
            }
#pragma unroll
            for (int p = 0; p < TH; p++) {
                float m = 0.f;
#pragma unroll
                for (int k = 0; k < KS; k++) m += w[k] * vs[p + k];
                mu[s][p] = m;
            }
        }

        const int grow = gy0 + r;
        const bool rowok = (grow < OH);
#pragma unroll
        for (int p = 0; p < TH; p++) {
            if (rowok && (c0 + p) < OW) {
                const float mux = mu[0][p], muy = mu[1][p];
                const float sxx = mu[2][p] - mux * mux;
                const float syy = mu[3][p] - muy * muy;
                const float sxy = mu[4][p] - mux * muy;
                const float num = (2.f * sxy + c2) * (2.f * mux * muy + c1);
                const float den = (sxx + syy + c2) * (mux * mux + muy * muy + c1);
                acc += num * __builtin_amdgcn_rcpf(den);
            }
        }
    }

    // ---- Reduction: wave shuffle -> cross-wave LDS -> one atomic/block ----
#pragma unroll
    for (int off = 32; off > 0; off >>= 1)
        acc += __shfl_down(acc, off, 64);

    if ((t & 63) == 0) wsum[t >> 6] = acc;
    __syncthreads();
    if (t == 0) {
        float s = 0.f;
#pragma unroll
        for (int i = 0; i < NTHREADS / 64; i++) s += wsum[i];
        atomicAdd(out, s * (1.0f / (float)TOTAL_OUT));
    }
}

extern "C" void kernel_launch(void* const* d_in, const int* in_sizes, int n_in,
                              void* d_out, int out_size, void* d_ws, size_t ws_size,
                              hipStream_t stream)
{
    const float* x   = (const float*)d_in[0];
    const float* y   = (const float*)d_in[1];
    const float* win = (const float*)d_in[2];
    float* out = (float*)d_out;

    zero_out_kernel<<<1, 1, 0, stream>>>(out);

    dim3 grid(NCHUNKS, NPLANES);   // (16, 48) = 768 blocks = exactly 3/CU, single round
    ssim_kernel<<<grid, NTHREADS, 0, stream>>>(x, y, win, out);
}

// Round 2
// 207.986 us; speedup vs baseline: 2.1130x; 2.1130x over previous
//
#include <hip/hip_runtime.h>
#include <math.h>

// Problem constants
#define KS    11
#define H     512
#define W     512
#define OH    502
#define OW    502
#define NPLANES 48
#define TOTAL_OUT (NPLANES * OH * OW)   // 12,096,192

// Full-width tiles: 512 input cols = 512 threads, 1 col/thread.
// TH=4 output rows per iteration, block marches down a 32-row chunk.
#define TH      4
#define IROWS   (TH + KS - 1)     // 14 input rows per iteration
#define LVW     524               // row stride in words: 16B-aligned; rows needn't avoid conflicts
                                  // (stage-2 lanes read the SAME row, lane-contiguous)
#define NTHREADS 512
#define CHUNK   32                // output rows per block
#define ITERS   (CHUNK / TH)      // 8
#define NCHUNKS 16                // 16*32 = 512 >= 502

__global__ void zero_out_kernel(float* out) { out[0] = 0.0f; }

// launch_bounds 2nd arg: under CUDA semantics (min BLOCKS/CU) 3 blocks -> 24 waves/CU
// -> 85-VGPR budget; under HIP waves/EU semantics -> 170. Either way no spill for ~70 live regs.
// (Round-1 lesson: (512,6) was honored as 6 blocks/CU -> 42-reg budget -> 525 MB scratch spill.)
__global__ __launch_bounds__(NTHREADS, 3) void ssim_kernel(
    const float* __restrict__ x,
    const float* __restrict__ y,
    const float* __restrict__ win,
    float* __restrict__ out)
{
    // 5 vertically-convolved signals: mu_x, mu_y, xx, yy, xy
    __shared__ __align__(16) float v[5][TH][LVW];   // 41,920 B -> 3 blocks/CU (24 waves = 75%)
    __shared__ float w1s[KS];
    __shared__ float wsum[NTHREADS / 64];

    const int t     = threadIdx.x;          // == input column in stage 1
    const int chunk = blockIdx.x;           // 0..15
    const int plane = blockIdx.y;           // 0..47

    const float* __restrict__ xp = x + (size_t)plane * (H * W);
    const float* __restrict__ yp = y + (size_t)plane * (H * W);

    // Separable taps: window = outer(g,g) => g[i] = sqrt(win[i][i])
    if (t < KS) w1s[t] = sqrtf(win[t * KS + t]);
    __syncthreads();

    float w[KS];
#pragma unroll
    for (int k = 0; k < KS; k++) w[k] = w1s[k];

    // Stage-2 mapping (conflict-free): whole wave reads ONE row, lane-contiguous cols.
    //   r = t>>7 (waves 0-1 -> row 0, ..., waves 6-7 -> row 3)
    //   c0 = (t&127)*4 : 0..508; reads words c0..c0+15 <= 523 < LVW.
    const int r  = t >> 7;
    const int c0 = (t & 127) << 2;
    const float c1 = 1e-4f;   // (0.01)^2
    const float c2 = 9e-4f;   // (0.03)^2
    float acc = 0.f;

    for (int it = 0; it < ITERS; ++it) {
        const int gy0 = chunk * CHUNK + it * TH;
        if (gy0 >= OH) break;               // uniform across block

        // ---- Stage 1: vertical 11-tap conv, 1 column/thread, regs only ----
        float a0[TH], a1[TH], a2[TH], a3[TH], a4[TH];
#pragma unroll
        for (int q = 0; q < TH; q++) { a0[q]=0.f; a1[q]=0.f; a2[q]=0.f; a3[q]=0.f; a4[q]=0.f; }

#pragma unroll
        for (int j = 0; j < IROWS; j++) {
            const int gy = gy0 + j;
            float xv = 0.f, yv = 0.f;
            if (gy < H) {                   // uniform branch
                xv = xp[gy * W + t];
                yv = yp[gy * W + t];
            }
            const float xx = xv * xv;
            const float yy = yv * yv;
            const float xy = xv * yv;
#pragma unroll
            for (int q = 0; q < TH; q++) {
                if (j - q >= 0 && j - q < KS) {   // constant-folds after unroll
                    const float wk = w[j - q];
                    a0[q] += wk * xv;
                    a1[q] += wk * yv;
                    a2[q] += wk * xx;
                    a3[q] += wk * yy;
                    a4[q] += wk * xy;
                }
            }
        }

        __syncthreads();    // WAR: previous iteration's stage-2 reads of v are done
#pragma unroll
        for (int q = 0; q < TH; q++) {      // lane==col -> consecutive words -> conflict-free
            v[0][q][t] = a0[q];
            v[1][q][t] = a1[q];
            v[2][q][t] = a2[q];
            v[3][q][t] = a3[q];
            v[4][q][t] = a4[q];
        }
        __syncthreads();    // v ready

        // ---- Stage 2: horizontal 11-tap conv over 4-px run + SSIM ----
        float mu[5][TH];
#pragma unroll
        for (int s = 0; s < 5; s++) {
            const float* __restrict__ vrow = &v[s][r][c0];   // 16B-aligned
            float vs[16];
#pragma unroll
            for (int qq = 0; qq < 4; qq++) {                 // 4x ds_read_b128, lane-contiguous
                const float4 f4 = *reinterpret_cast<const float4*>(vrow + 4 * qq);
                vs[4*qq+0] = f4.x; vs[4*qq+1] = f4.y; vs[4*qq+2] = f4.z; vs[4*qq+3] = f4.w;
            }
#pragma unroll
            for (int p = 0; p < TH; p++) {
                float m = 0.f;
#pragma unroll
                for (int k = 0; k < KS; k++) m += w[k] * vs[p + k];
                mu[s][p] = m;
            }
        }

        const int grow = gy0 + r;
        const bool rowok = (grow < OH);
#pragma unroll
        for (int p = 0; p < TH; p++) {
            if (rowok && (c0 + p) < OW) {
                const float mux = mu[0][p], muy = mu[1][p];
                const float sxx = mu[2][p] - mux * mux;
                const float syy = mu[3][p] - muy * muy;
                const float sxy = mu[4][p] - mux * muy;
                const float num = (2.f * sxy + c2) * (2.f * mux * muy + c1);
                const float den = (sxx + syy + c2) * (mux * mux + muy * muy + c1);
                acc += num * __builtin_amdgcn_rcpf(den);
            }
        }
    }

    // ---- Reduction: wave shuffle -> cross-wave LDS -> one atomic/block ----
#pragma unroll
    for (int off = 32; off > 0; off >>= 1)
        acc += __shfl_down(acc, off, 64);

    if ((t & 63) == 0) wsum[t >> 6] = acc;
    __syncthreads();
    if (t == 0) {
        float s = 0.f;
#pragma unroll
        for (int i = 0; i < NTHREADS / 64; i++) s += wsum[i];
        atomicAdd(out, s * (1.0f / (float)TOTAL_OUT));
    }
}

extern "C" void kernel_launch(void* const* d_in, const int* in_sizes, int n_in,
                              void* d_out, int out_size, void* d_ws, size_t ws_size,
                              hipStream_t stream)
{
    const float* x   = (const float*)d_in[0];
    const float* y   = (const float*)d_in[1];
    const float* win = (const float*)d_in[2];
    float* out = (float*)d_out;

    zero_out_kernel<<<1, 1, 0, stream>>>(out);

    dim3 grid(NCHUNKS, NPLANES);   // (16, 48) = 768 blocks = exactly 3/CU, single round
    ssim_kernel<<<grid, NTHREADS, 0, stream>>>(x, y, win, out);
}

// Round 3
// 161.561 us; speedup vs baseline: 2.7202x; 1.2873x over previous
//
#include <hip/hip_runtime.h>
#include <math.h>

// Problem constants
#define KS    11
#define H     512
#define W     512
#define OH    502
#define OW    502
#define NPLANES 48
#define TOTAL_OUT (NPLANES * OH * OW)   // 12,096,192

// Full-width 512-thread blocks, TH=8 output rows/iter, 4 signals (xx+yy fused).
#define TH      8
#define IROWS   (TH + KS - 1)     // 18 input rows per iteration
#define NSIG    4                 // mu_x, mu_y, conv(x^2+y^2), conv(xy)
#define LVW     523               // ODD row stride (words): 11r+8u spreads banks -> 2-way = free
#define NTHREADS 512
#define NCHUNKS 10                // 10 x 51 = 510 >= 502 rows
#define CROWS   51                // rows per chunk (last chunk: 43)

__global__ void zero_out_kernel(float* out) { out[0] = 0.0f; }

// 2nd arg is min BLOCKS/CU on this compiler (round-1 evidence: (512,6)->42-reg budget).
// 2 blocks/CU -> 16 waves -> 128-VGPR budget; LDS (66.9 KB) also caps at 2 blocks.
__global__ __launch_bounds__(NTHREADS, 2) void ssim_kernel(
    const float* __restrict__ x,
    const float* __restrict__ y,
    const float* __restrict__ win,
    float* __restrict__ out)
{
    __shared__ float v[NSIG][TH][LVW];   // 66,944 B -> 2 blocks/CU
    __shared__ float w1s[KS];
    __shared__ float wsum[NTHREADS / 64];

    const int t     = threadIdx.x;          // == input column
    const int chunk = blockIdx.x;           // 0..9
    const int plane = blockIdx.y;           // 0..47

    const int row_lo = chunk * CROWS;
    const int row_hi = (row_lo + CROWS < OH) ? (row_lo + CROWS) : OH;
    const int niter  = (row_hi - row_lo + TH - 1) / TH;   // 7 (chunks 0-8) or 6 (chunk 9)

    const float* __restrict__ xp = x + (size_t)plane * (H * W);
    const float* __restrict__ yp = y + (size_t)plane * (H * W);

    // Separable taps: window = outer(g,g) => g[i] = sqrt(win[i][i])
    if (t < KS) w1s[t] = sqrtf(win[t * KS + t]);
    __syncthreads();

    float w[KS];
#pragma unroll
    for (int k = 0; k < KS; k++) w[k] = w1s[k];

    // Stage-2 mapping (round-0 verified conflict-free): 8 rows x 64 runs of 8 px.
    // bank = (523*r + 8*(t>>3) + j) mod 32 = (11r + 8u + j) mod 32 -> 2 lanes/bank.
    const int r  = t & 7;
    const int c0 = (t >> 3) << 3;            // 0..504; reads words c0..c0+17 <= 521 < 523
    const float c1 = 1e-4f;   // (0.01)^2
    const float c2 = 9e-4f;   // (0.03)^2
    float acc = 0.f;

    // Raw input rows for the CURRENT iteration (software pipeline: loaded one iter early).
    float rx[IROWS], ry[IROWS];
    {
        // All input rows 0..511 are legal (output row 501's window ends at row 511).
        // Clamp: clamped rows only pollute output rows >= 502, discarded by grow<row_hi.
#pragma unroll
        for (int j = 0; j < IROWS; j++) {
            int gy = row_lo + j; gy = (gy < H - 1) ? gy : (H - 1);
            rx[j] = xp[gy * W + t];
            ry[j] = yp[gy * W + t];
        }
    }

    for (int it = 0; it < niter; ++it) {
        const int gy0 = row_lo + it * TH;

        // ---- Stage 1: vertical 11-tap conv from prefetched regs ----
        float a0[TH], a1[TH], a2[TH], a3[TH];
#pragma unroll
        for (int q = 0; q < TH; q++) { a0[q]=0.f; a1[q]=0.f; a2[q]=0.f; a3[q]=0.f; }

#pragma unroll
        for (int j = 0; j < IROWS; j++) {
            const float xv = rx[j], yv = ry[j];
            const float pss = xv * xv + yv * yv;   // fused x^2+y^2 signal
            const float pxy = xv * yv;
#pragma unroll
            for (int q = 0; q < TH; q++) {
                if (j - q >= 0 && j - q < KS) {    // constant-folds after unroll
                    const float wk = w[j - q];
                    a0[q] += wk * xv;
                    a1[q] += wk * yv;
                    a2[q] += wk * pss;
                    a3[q] += wk * pxy;
                }
            }
        }

        __syncthreads();    // WAR: previous iteration's stage-2 reads of v are done
#pragma unroll
        for (int q = 0; q < TH; q++) {      // lane==col -> stride-1 words -> conflict-free
            v[0][q][t] = a0[q];
            v[1][q][t] = a1[q];
            v[2][q][t] = a2[q];
            v[3][q][t] = a3[q];
        }
        __syncthreads();    // v ready

        // ---- Prefetch next iteration's raw rows (issued here, consumed after loop-back;
        //      no barrier in between -> latency hides under hconv below) ----
        if (it + 1 < niter) {
            const int ny0 = row_lo + (it + 1) * TH;
#pragma unroll
            for (int j = 0; j < IROWS; j++) {
                int gy = ny0 + j; gy = (gy < H - 1) ? gy : (H - 1);
                rx[j] = xp[gy * W + t];
                ry[j] = yp[gy * W + t];
            }
        }

        // ---- Stage 2: horizontal 11-tap conv over 8-px run + SSIM ----
        float mu[NSIG][TH];
#pragma unroll
        for (int s = 0; s < NSIG; s++) {
            const float* __restrict__ vrow = &v[s][r][c0];
            float vs[IROWS];
#pragma unroll
            for (int j = 0; j < IROWS; j++) vs[j] = vrow[j];   // scalar b32, conflict-free
#pragma unroll
            for (int p = 0; p < TH; p++) {
                float m = 0.f;
#pragma unroll
                for (int k = 0; k < KS; k++) m += w[k] * vs[p + k];
                mu[s][p] = m;
            }
        }

        const int grow  = gy0 + r;
        const bool rowok = (grow < row_hi);
#pragma unroll
        for (int p = 0; p < TH; p++) {
            if (rowok && (c0 + p) < OW) {
                const float mux = mu[0][p], muy = mu[1][p];
                const float mxy = mux * muy;
                const float m2  = mux * mux + muy * muy;
                const float sss = mu[2][p] - m2;        // sigma_x^2 + sigma_y^2
                const float sxy = mu[3][p] - mxy;
                const float num = (2.f * sxy + c2) * (2.f * mxy + c1);
                const float den = (sss + c2) * (m2 + c1);
                acc += num * __builtin_amdgcn_rcpf(den);
            }
        }
    }

    // ---- Reduction: wave shuffle -> cross-wave LDS -> one atomic/block ----
#pragma unroll
    for (int off = 32; off > 0; off >>= 1)
        acc += __shfl_down(acc, off, 64);

    if ((t & 63) == 0) wsum[t >> 6] = acc;
    __syncthreads();
    if (t == 0) {
        float s = 0.f;
#pragma unroll
        for (int i = 0; i < NTHREADS / 64; i++) s += wsum[i];
        atomicAdd(out, s * (1.0f / (float)TOTAL_OUT));
    }
}

extern "C" void kernel_launch(void* const* d_in, const int* in_sizes, int n_in,
                              void* d_out, int out_size, void* d_ws, size_t ws_size,
                              hipStream_t stream)
{
    const float* x   = (const float*)d_in[0];
    const float* y   = (const float*)d_in[1];
    const float* win = (const float*)d_in[2];
    float* out = (float*)d_out;

    zero_out_kernel<<<1, 1, 0, stream>>>(out);

    // 480 blocks <= 512 resident slots (2/CU x 256) -> all blocks resident from t=0,
    // no scheduling rounds, no tail imbalance.
    dim3 grid(NCHUNKS, NPLANES);
    ssim_kernel<<<grid, NTHREADS, 0, stream>>>(x, y, win, out);
}